// Round 1
// baseline (303.872 us; speedup 1.0000x reference)
//
#include <hip/hip_runtime.h>
#include <math.h>

// Problem constants (from setup_inputs): B=8, S=8192, D=1024, 64 hidden units.
#define BATCH 8
#define SEQ   8192
#define DIM   1024

// out[b,d] = iw[A-1,d] * sum_a w[a] * hs[b, idx[a], d]
// where idx/counts are derived from `position` on device (only spine values
// {0,1,2,5} can ever qualify: pc keys need position<=12 and sp<position).
__global__ __launch_bounds__(256) void flfa_kernel(
    const float* __restrict__ hs,   // (B, SEQ, DIM)
    const float* __restrict__ iw,   // (10, DIM)
    const float* __restrict__ w1,   // (64,1) -> w1[j]
    const float* __restrict__ b1,   // (64,)
    const float* __restrict__ w2,   // (1,64) -> w2[j]
    const float* __restrict__ b2,   // (1,)
    const int* __restrict__ posp,   // scalar position
    float* __restrict__ out)        // (B, DIM)
{
    __shared__ float s_w[4];
    __shared__ int   s_idx[4];
    __shared__ int   s_A;

    const int tid = threadIdx.x;
    const int b   = blockIdx.x;

    // ---- setup: first wave (64 lanes) computes anchors, counts, MLP weights ----
    if (tid < 64) {
        const int position = *posp;
        const int spine_vals[4] = {0, 1, 2, 5};
        int   A = 0;
        int   idxs[4];
        float cnts[4];
        if (position >= 1 && position <= 12) {       // pc membership bound
            for (int s = 0; s < 4; ++s) {
                const int sp = spine_vals[s];
                if (sp < position) {
                    // pc[sp][position] = t_k, k=position-sp; t1=1, t2=2, t_k=t_{k-1}+t_{k-2}
                    const int k = position - sp;
                    float c;
                    if (k == 1)      c = 1.0f;
                    else if (k == 2) c = 2.0f;
                    else {
                        float ta = 1.0f, tb = 2.0f;
                        for (int q = 3; q <= k; ++q) { float t = ta + tb; ta = tb; tb = t; }
                        c = tb;
                    }
                    idxs[A] = sp; cnts[A] = c; ++A;
                }
            }
        }

        // MLP: lane j owns hidden unit j. h = relu(c*w1[j]+b1[j]) * w2[j],
        // reduce over 64 lanes, softplus, accumulate normalizer.
        const float w1j = w1[tid];
        const float b1j = b1[tid];
        const float w2j = w2[tid];
        const float b2v = b2[0];
        float wv[4];
        float wsum = 0.0f;
        for (int a = 0; a < A; ++a) {                // A is wave-uniform
            float h = fmaxf(fmaf(cnts[a], w1j, b1j), 0.0f) * w2j;
            #pragma unroll
            for (int off = 32; off > 0; off >>= 1)
                h += __shfl_down(h, off, 64);
            const float z  = __shfl(h, 0, 64) + b2v;
            // numerically-stable softplus: max(z,0) + log1p(exp(-|z|))
            const float sp = fmaxf(z, 0.0f) + log1pf(expf(-fabsf(z)));
            wv[a] = sp;
            wsum += sp;
        }
        if (tid == 0) {
            s_A = A;
            for (int a = 0; a < A; ++a) {
                s_idx[a] = idxs[a];
                s_w[a]   = wv[a] / wsum;
            }
        }
    }
    __syncthreads();

    // ---- main: each thread computes 4 consecutive d via float4 (coalesced) ----
    const int A = s_A;
    const int d = tid * 4;
    float4 acc = make_float4(0.0f, 0.0f, 0.0f, 0.0f);
    for (int a = 0; a < A; ++a) {
        const float4 h4 = *(const float4*)(hs + ((size_t)b * SEQ + s_idx[a]) * DIM + d);
        const float wa = s_w[a];
        acc.x = fmaf(wa, h4.x, acc.x);
        acc.y = fmaf(wa, h4.y, acc.y);
        acc.z = fmaf(wa, h4.z, acc.z);
        acc.w = fmaf(wa, h4.w, acc.w);
    }
    if (A > 0) {
        const float4 iw4 = *(const float4*)(iw + (size_t)(A - 1) * DIM + d);
        acc.x *= iw4.x; acc.y *= iw4.y; acc.z *= iw4.z; acc.w *= iw4.w;
    }
    *(float4*)(out + (size_t)b * DIM + d) = acc;   // zeros when A==0
}

extern "C" void kernel_launch(void* const* d_in, const int* in_sizes, int n_in,
                              void* d_out, int out_size, void* d_ws, size_t ws_size,
                              hipStream_t stream) {
    const float* hs  = (const float*)d_in[0];
    const float* iw  = (const float*)d_in[1];
    const float* w1  = (const float*)d_in[2];
    const float* b1  = (const float*)d_in[3];
    const float* w2  = (const float*)d_in[4];
    const float* b2  = (const float*)d_in[5];
    const int*   pos = (const int*)d_in[6];
    float* out = (float*)d_out;

    flfa_kernel<<<dim3(BATCH), dim3(256), 0, stream>>>(hs, iw, w1, b1, w2, b2, pos, out);
}